// Round 8
// baseline (114.799 us; speedup 1.0000x reference)
//
#include <hip/hip_runtime.h>

// Fused SNN forward for MI355X (gfx950) — round 8.
// Regime (rounds 6-7 evidence): fp32-ALU-cycle-bound, VALUBusy ~90%.
// fp32 pk ops cost 2x scalar ALU cycles (157TF peak == scalar fma rate),
// so only real-op removal helps:
//  - fold+xor16 fused via dual-register v_permlane16_swap(v0,v2): 5 ops -> 2
//  - FC de-packed to scalar fmas (pk gave no cycles, cost splat movs)
//  - waves_per_eu(4) min-only (no max cap)

typedef float v2f __attribute__((ext_vector_type(2)));
typedef unsigned v2u __attribute__((ext_vector_type(2)));

#if __has_builtin(__builtin_elementwise_fma)
#define VFMA(a, b, c) __builtin_elementwise_fma((a), (b), (c))
#else
#define VFMA(a, b, c) ((a) * (b) + (c))
#endif

// x + x[lane^16]  (VALU permlane, no LDS traffic)
__device__ __forceinline__ float bfly16(float x) {
#if __has_builtin(__builtin_amdgcn_permlane16_swap)
    v2u r = __builtin_amdgcn_permlane16_swap(__float_as_uint(x), __float_as_uint(x),
                                             false, false);
    return __uint_as_float(r.x) + __uint_as_float(r.y);
#else
    return x + __shfl_xor(x, 16);
#endif
}

// Fused fold + xor16: returns (lane&16)==0 ? a + a[l^16] : b + b[l^16].
// permlane16_swap(a,b) exchanges 16-lane rows between the two registers;
// the SUM of its two outputs is row-symmetric, so dst0/dst1 role ambiguity
// cancels.
__device__ __forceinline__ float pairfold16(float a, float b) {
#if __has_builtin(__builtin_amdgcn_permlane16_swap)
    v2u r = __builtin_amdgcn_permlane16_swap(__float_as_uint(a), __float_as_uint(b),
                                             false, false);
    return __uint_as_float(r.x) + __uint_as_float(r.y);
#else
    const float sa = a + __shfl_xor(a, 16);
    const float sb = b + __shfl_xor(b, 16);
    return ((threadIdx.x & 16) != 0) ? sb : sa;
#endif
}

// value held by lane^32 via v_permlane32_swap
__device__ __forceinline__ float partner32(float x, bool hi) {
#if __has_builtin(__builtin_amdgcn_permlane32_swap)
    v2u r = __builtin_amdgcn_permlane32_swap(__float_as_uint(x), __float_as_uint(x),
                                             false, false);
    return __uint_as_float(hi ? r.x : r.y);
#else
    (void)hi;
    return __shfl_xor(x, 32);
#endif
}

// x + row_ror:N(x) within each 16-lane row. N=8 == xor8; N=4 after the
// N=8 level (values period-8) == xor4.
template<int N>
__device__ __forceinline__ float dpp_ror_add(float x) {
#if __has_builtin(__builtin_amdgcn_update_dpp)
    int y = __builtin_amdgcn_update_dpp(0, __float_as_int(x), 0x120 + N, 0xf, 0xf, false);
    return x + __int_as_float(y);
#else
    return x + __shfl_xor(x, N);
#endif
}

__attribute__((amdgpu_waves_per_eu(4)))
__global__ __launch_bounds__(512) void snn_fused_kernel(
    const float* __restrict__ x,       // [4096, 1, 28, 28]
    const float* __restrict__ conv_w,  // [8, 1, 3, 3]
    const float* __restrict__ fc_w,    // [10, 1352]
    float* __restrict__ out)           // [4096, 10]
{
    const int b    = blockIdx.x;
    const int tid  = threadIdx.x;
    const int lane = tid & 63;
    const int wid  = tid >> 6;

    __shared__ float sx[784];            // 28x28 image
    __shared__ float scw[72];            // conv weights
    __shared__ float sred[32 * 165];     // 32 rows x (16t*10o), stride 165
    __shared__ float scur2[160];         // [t][o]

    {
        const float4* xg  = reinterpret_cast<const float4*>(x + (size_t)b * 784);
        float4*       sx4 = reinterpret_cast<float4*>(sx);
        if (tid < 196) sx4[tid] = xg[tid];
        if (tid < 72)  scw[tid] = conv_w[tid];
    }
    __syncthreads();

    const bool hi32 = (lane & 32) != 0;

    // ---- per-thread state ----
    v2f cur2[3][2];        // conv out: [unit][{cells01, cells23}]
    v2f mem2[3][2];        // LIF-1 membranes
    float wl[6][5];        // 0.25*fc_w: j<3 own units, j>=3 partner units;
                           // k -> output o = hi32 ? k+5 : k

    #pragma unroll
    for (int i = 0; i < 3; ++i) {
        const int u      = tid + 512 * i;
        const bool valid = (u < 1352);
        const int uu  = valid ? u : 0;
        const int k   = uu / 169;
        const int rem = uu - k * 169;
        const int pr  = rem / 13;
        const int pc  = rem - pr * 13;

        float cw[9];
        #pragma unroll
        for (int q = 0; q < 9; ++q) cw[q] = scw[k * 9 + q];

        float xr[4][4];
        #pragma unroll
        for (int r = 0; r < 4; ++r) {
            const float2* row = reinterpret_cast<const float2*>(&sx[(2 * pr + r) * 28 + 2 * pc]);
            const float2 a = row[0], c2 = row[1];
            xr[r][0] = a.x; xr[r][1] = a.y; xr[r][2] = c2.x; xr[r][3] = c2.y;
        }

        float cell[2][2];
        #pragma unroll
        for (int dr = 0; dr < 2; ++dr)
            #pragma unroll
            for (int dc = 0; dc < 2; ++dc) {
                float acc = 0.0f;
                #pragma unroll
                for (int ki = 0; ki < 3; ++ki)
                    #pragma unroll
                    for (int kj = 0; kj < 3; ++kj)
                        acc += xr[dr + ki][dc + kj] * cw[ki * 3 + kj];
                cell[dr][dc] = valid ? acc : 0.0f;
            }
        cur2[i][0] = (v2f){cell[0][0], cell[0][1]};
        cur2[i][1] = (v2f){cell[1][0], cell[1][1]};
        mem2[i][0] = (v2f){0.0f, 0.0f};
        mem2[i][1] = (v2f){0.0f, 0.0f};
    }

    // weights: own units (j=0..2) and lane^32-partner units (j=3..5)
    #pragma unroll
    for (int j = 0; j < 6; ++j) {
        const int bt     = (j < 3) ? tid : (tid ^ 32);
        const int u      = bt + 512 * (j % 3);
        const bool valid = (u < 1352);
        const int uu     = valid ? u : 0;
        const int ob     = hi32 ? 5 : 0;
        const float sc   = valid ? 0.25f : 0.0f;
        #pragma unroll
        for (int k = 0; k < 5; ++k)
            wl[j][k] = sc * fc_w[(ob + k) * 1352 + uu];
    }

    const v2f half2 = (v2f){0.5f, 0.5f};

    // stageA: one LIF step on own units + permlane count exchange + scalar FC
    auto stageA = [&](float& n0, float& n1, float& n2, float& n3, float& n4) {
        float c[3];
        #pragma unroll
        for (int i = 0; i < 3; ++i) {
            v2f m01 = VFMA(half2, mem2[i][0], cur2[i][0]);
            v2f m23 = VFMA(half2, mem2[i][1], cur2[i][1]);
            v2f sp01, sp23;
            sp01.x = m01.x > 1.0f ? 1.0f : 0.0f;   // spike iff m > THR
            sp01.y = m01.y > 1.0f ? 1.0f : 0.0f;
            sp23.x = m23.x > 1.0f ? 1.0f : 0.0f;
            sp23.y = m23.y > 1.0f ? 1.0f : 0.0f;
            mem2[i][0] = m01 - sp01;               // subtract-reset (bit-identical)
            mem2[i][1] = m23 - sp23;
            c[i] = (sp01.x + sp01.y) + (sp23.x + sp23.y);   // 0..4 exact
        }
        float p[3];
        p[0] = partner32(c[0], hi32);
        p[1] = partner32(c[1], hi32);
        p[2] = partner32(c[2], hi32);

        n0 = n1 = n2 = n3 = n4 = 0.0f;
        #pragma unroll
        for (int i = 0; i < 3; ++i) {              // own units (hide swap latency)
            n0 = __builtin_fmaf(wl[i][0], c[i], n0);
            n1 = __builtin_fmaf(wl[i][1], c[i], n1);
            n2 = __builtin_fmaf(wl[i][2], c[i], n2);
            n3 = __builtin_fmaf(wl[i][3], c[i], n3);
            n4 = __builtin_fmaf(wl[i][4], c[i], n4);
        }
        #pragma unroll
        for (int i = 0; i < 3; ++i) {              // partner units
            n0 = __builtin_fmaf(wl[3 + i][0], p[i], n0);
            n1 = __builtin_fmaf(wl[3 + i][1], p[i], n1);
            n2 = __builtin_fmaf(wl[3 + i][2], p[i], n2);
            n3 = __builtin_fmaf(wl[3 + i][3], p[i], n3);
            n4 = __builtin_fmaf(wl[3 + i][4], p[i], n4);
        }
    };

    float v0, v1, v2, v3, v4;
    stageA(v0, v1, v2, v3, v4);                    // t = 0 partials

    const int q   = lane >> 4;                     // quadrant 0..3
    const int bo  = (q & 1) * 2 + (q >> 1) * 5;    // {0,2,5,7}
    const int to  = 4 + (q >> 1) * 5;              // {4,4,9,9}
    const int row = wid * 4 + (lane & 3);          // 32 rows total

    #pragma unroll
    for (int t = 0; t < 16; ++t) {
        // fused fold + xor16 (1 permlane + 1 add each), then next stageA
        float w0 = pairfold16(v0, v2);
        float w1 = pairfold16(v1, v3);
        float w2 = bfly16(v4);

        float n0, n1, n2, n3, n4;
        if (t < 15) {
            stageA(n0, n1, n2, n3, n4);
        } else {
            n0 = n1 = n2 = n3 = n4 = 0.0f;
        }

        // xor8 / xor4 via DPP row_ror adds
        w0 = dpp_ror_add<8>(w0);
        w1 = dpp_ror_add<8>(w1);
        w2 = dpp_ror_add<8>(w2);
        w0 = dpp_ror_add<4>(w0);
        w1 = dpp_ror_add<4>(w1);
        w2 = dpp_ror_add<4>(w2);

        // 4 rows per wave; duplicate equal-value writes of w2 are benign
        if ((lane & 12) == 0) {
            const int base = row * 165 + t * 10;
            sred[base + bo]     = w0;
            sred[base + bo + 1] = w1;
            sred[base + to]     = w2;
        }

        v0 = n0; v1 = n1; v2 = n2; v3 = n3; v4 = n4;
    }
    __syncthreads();

    // ---- final reduce: 160 threads, one (t,o) each, 32 rows ----
    if (tid < 160) {
        float sum = 0.0f;
        #pragma unroll
        for (int r = 0; r < 32; ++r)
            sum += sred[r * 165 + tid];
        scur2[tid] = sum;
    }
    __syncthreads();

    // ---- LIF-2 scan, 10 lanes ----
    if (tid < 10) {
        float m2 = 0.0f, cnt = 0.0f;
        #pragma unroll
        for (int t = 0; t < 16; ++t) {
            m2 = __builtin_fmaf(0.5f, m2, scur2[t * 10 + tid]);
            float ms = m2 - 1.0f;
            bool  sp = ms > 0.0f;
            m2  = sp ? ms : m2;
            cnt += sp ? 1.0f : 0.0f;
        }
        out[(size_t)b * 10 + tid] = cnt;
    }
}

extern "C" void kernel_launch(void* const* d_in, const int* in_sizes, int n_in,
                              void* d_out, int out_size, void* d_ws, size_t ws_size,
                              hipStream_t stream) {
    const float* x      = (const float*)d_in[0];  // 4096*784
    const float* conv_w = (const float*)d_in[1];  // 72
    const float* fc_w   = (const float*)d_in[2];  // 13520
    float* out          = (float*)d_out;          // 40960

    const int B = in_sizes[0] / 784;              // 4096
    snn_fused_kernel<<<B, 512, 0, stream>>>(x, conv_w, fc_w, out);
}

// Round 9
// 105.771 us; speedup vs baseline: 1.0853x; 1.0853x over previous
//
#include <hip/hip_runtime.h>

// Fused SNN forward for MI355X (gfx950) — round 9.
// Combine round 6 (fully packed dual-fp32 math: v_pk_fma_f32 is FULL RATE,
// 157TF = 2x scalar) with round 8 (reduction entirely on VALU permlane/DPP,
// only 3 DS writes per wave per timestep). r6 was DS-limited, r8 was
// unpacked; this is the union of both fixes.

typedef float v2f __attribute__((ext_vector_type(2)));
typedef unsigned v2u __attribute__((ext_vector_type(2)));

#if __has_builtin(__builtin_elementwise_fma)
#define VFMA(a, b, c) __builtin_elementwise_fma((a), (b), (c))
#else
#define VFMA(a, b, c) ((a) * (b) + (c))
#endif

// x + x[lane^16]  (VALU permlane, no LDS traffic)
__device__ __forceinline__ float bfly16(float x) {
#if __has_builtin(__builtin_amdgcn_permlane16_swap)
    v2u r = __builtin_amdgcn_permlane16_swap(__float_as_uint(x), __float_as_uint(x),
                                             false, false);
    return __uint_as_float(r.x) + __uint_as_float(r.y);
#else
    return x + __shfl_xor(x, 16);
#endif
}

// Fused fold + xor16: (lane&16)==0 ? a + a[l^16] : b + b[l^16].
// The SUM of permlane16_swap's two outputs is row-symmetric, so dst role
// ambiguity cancels.
__device__ __forceinline__ float pairfold16(float a, float b) {
#if __has_builtin(__builtin_amdgcn_permlane16_swap)
    v2u r = __builtin_amdgcn_permlane16_swap(__float_as_uint(a), __float_as_uint(b),
                                             false, false);
    return __uint_as_float(r.x) + __uint_as_float(r.y);
#else
    const float sa = a + __shfl_xor(a, 16);
    const float sb = b + __shfl_xor(b, 16);
    return ((threadIdx.x & 16) != 0) ? sb : sa;
#endif
}

// value held by lane^32 via v_permlane32_swap
__device__ __forceinline__ float partner32(float x, bool hi) {
#if __has_builtin(__builtin_amdgcn_permlane32_swap)
    v2u r = __builtin_amdgcn_permlane32_swap(__float_as_uint(x), __float_as_uint(x),
                                             false, false);
    return __uint_as_float(hi ? r.x : r.y);
#else
    (void)hi;
    return __shfl_xor(x, 32);
#endif
}

// x + row_ror:N(x) within each 16-lane row. N=8 == xor8; N=4 after the
// N=8 level (values period-8) == xor4.
template<int N>
__device__ __forceinline__ float dpp_ror_add(float x) {
#if __has_builtin(__builtin_amdgcn_update_dpp)
    int y = __builtin_amdgcn_update_dpp(0, __float_as_int(x), 0x120 + N, 0xf, 0xf, false);
    return x + __int_as_float(y);
#else
    return x + __shfl_xor(x, N);
#endif
}

__global__ __launch_bounds__(512, 4) void snn_fused_kernel(
    const float* __restrict__ x,       // [4096, 1, 28, 28]
    const float* __restrict__ conv_w,  // [8, 1, 3, 3]
    const float* __restrict__ fc_w,    // [10, 1352]
    float* __restrict__ out)           // [4096, 10]
{
    const int b    = blockIdx.x;
    const int tid  = threadIdx.x;
    const int lane = tid & 63;
    const int wid  = tid >> 6;

    __shared__ float sx[784];            // 28x28 image
    __shared__ float scw[72];            // conv weights
    __shared__ float sred[32 * 165];     // 32 rows x (16t*10o), stride 165
    __shared__ float scur2[160];         // [t][o]

    {
        const float4* xg  = reinterpret_cast<const float4*>(x + (size_t)b * 784);
        float4*       sx4 = reinterpret_cast<float4*>(sx);
        if (tid < 196) sx4[tid] = xg[tid];
        if (tid < 72)  scw[tid] = conv_w[tid];
    }
    __syncthreads();

    const bool hi32 = (lane & 32) != 0;

    // ---- per-thread state (packed) ----
    v2f cur2[3][2];        // conv out: [unit][{cells01, cells23}]
    v2f mem2[3][2];        // LIF-1 membranes
    v2f wl01[6], wl23[6];  // 0.25*fc_w for outputs {k0,k1},{k2,k3}
    float wl4[6];          // output k4

    #pragma unroll
    for (int i = 0; i < 3; ++i) {
        const int u      = tid + 512 * i;
        const bool valid = (u < 1352);
        const int uu  = valid ? u : 0;
        const int k   = uu / 169;
        const int rem = uu - k * 169;
        const int pr  = rem / 13;
        const int pc  = rem - pr * 13;

        float cw[9];
        #pragma unroll
        for (int q = 0; q < 9; ++q) cw[q] = scw[k * 9 + q];

        float xr[4][4];
        #pragma unroll
        for (int r = 0; r < 4; ++r) {
            const float2* row = reinterpret_cast<const float2*>(&sx[(2 * pr + r) * 28 + 2 * pc]);
            const float2 a = row[0], c2 = row[1];
            xr[r][0] = a.x; xr[r][1] = a.y; xr[r][2] = c2.x; xr[r][3] = c2.y;
        }

        float cell[2][2];
        #pragma unroll
        for (int dr = 0; dr < 2; ++dr)
            #pragma unroll
            for (int dc = 0; dc < 2; ++dc) {
                float acc = 0.0f;
                #pragma unroll
                for (int ki = 0; ki < 3; ++ki)
                    #pragma unroll
                    for (int kj = 0; kj < 3; ++kj)
                        acc += xr[dr + ki][dc + kj] * cw[ki * 3 + kj];
                cell[dr][dc] = valid ? acc : 0.0f;
            }
        cur2[i][0] = (v2f){cell[0][0], cell[0][1]};
        cur2[i][1] = (v2f){cell[1][0], cell[1][1]};
        mem2[i][0] = (v2f){0.0f, 0.0f};
        mem2[i][1] = (v2f){0.0f, 0.0f};
    }

    // weights: own units (j=0..2) and lane^32-partner units (j=3..5)
    #pragma unroll
    for (int j = 0; j < 6; ++j) {
        const int bt     = (j < 3) ? tid : (tid ^ 32);
        const int u      = bt + 512 * (j % 3);
        const bool valid = (u < 1352);
        const int uu     = valid ? u : 0;
        const int ob     = hi32 ? 5 : 0;
        const float sc   = valid ? 0.25f : 0.0f;
        wl01[j] = (v2f){sc * fc_w[(ob + 0) * 1352 + uu], sc * fc_w[(ob + 1) * 1352 + uu]};
        wl23[j] = (v2f){sc * fc_w[(ob + 2) * 1352 + uu], sc * fc_w[(ob + 3) * 1352 + uu]};
        wl4[j]  = sc * fc_w[(ob + 4) * 1352 + uu];
    }

    const v2f half2 = (v2f){0.5f, 0.5f};

    // stageA: packed LIF on own units + permlane count exchange + packed FC
    auto stageA = [&](v2f& nv01, v2f& nv23, float& nv4) {
        float c[3];
        #pragma unroll
        for (int i = 0; i < 3; ++i) {
            v2f m01 = VFMA(half2, mem2[i][0], cur2[i][0]);
            v2f m23 = VFMA(half2, mem2[i][1], cur2[i][1]);
            v2f sp01, sp23;
            sp01.x = m01.x > 1.0f ? 1.0f : 0.0f;   // spike iff m > THR
            sp01.y = m01.y > 1.0f ? 1.0f : 0.0f;
            sp23.x = m23.x > 1.0f ? 1.0f : 0.0f;
            sp23.y = m23.y > 1.0f ? 1.0f : 0.0f;
            mem2[i][0] = m01 - sp01;               // subtract-reset (bit-identical)
            mem2[i][1] = m23 - sp23;
            v2f s = sp01 + sp23;
            c[i] = s.x + s.y;                      // 0..4 exact
        }
        float p[3];
        p[0] = partner32(c[0], hi32);
        p[1] = partner32(c[1], hi32);
        p[2] = partner32(c[2], hi32);

        nv01 = (v2f){0.0f, 0.0f};
        nv23 = (v2f){0.0f, 0.0f};
        nv4  = 0.0f;
        #pragma unroll
        for (int i = 0; i < 3; ++i) {              // own units (hide swap latency)
            const v2f f2 = (v2f){c[i], c[i]};      // folds into pk op_sel
            nv01 = VFMA(wl01[i], f2, nv01);
            nv23 = VFMA(wl23[i], f2, nv23);
            nv4  = __builtin_fmaf(wl4[i], c[i], nv4);
        }
        #pragma unroll
        for (int i = 0; i < 3; ++i) {              // partner units
            const v2f f2 = (v2f){p[i], p[i]};
            nv01 = VFMA(wl01[3 + i], f2, nv01);
            nv23 = VFMA(wl23[3 + i], f2, nv23);
            nv4  = __builtin_fmaf(wl4[3 + i], p[i], nv4);
        }
    };

    v2f v01, v23; float v4;
    stageA(v01, v23, v4);                          // t = 0 partials

    const int q   = lane >> 4;                     // quadrant 0..3
    const int bo  = (q & 1) * 2 + (q >> 1) * 5;    // {0,2,5,7}
    const int to  = 4 + (q >> 1) * 5;              // {4,4,9,9}
    const int row = wid * 4 + (lane & 3);          // 32 rows total

    #pragma unroll
    for (int t = 0; t < 16; ++t) {
        // fused fold + xor16 (1 permlane + 1 add each)
        float w0 = pairfold16(v01.x, v23.x);
        float w1 = pairfold16(v01.y, v23.y);
        float w2 = bfly16(v4);

        v2f nv01, nv23; float nv4;
        if (t < 15) {
            stageA(nv01, nv23, nv4);
        } else {
            nv01 = (v2f){0.0f, 0.0f};
            nv23 = (v2f){0.0f, 0.0f};
            nv4  = 0.0f;
        }

        // xor8 / xor4 via DPP row_ror adds
        w0 = dpp_ror_add<8>(w0);
        w1 = dpp_ror_add<8>(w1);
        w2 = dpp_ror_add<8>(w2);
        w0 = dpp_ror_add<4>(w0);
        w1 = dpp_ror_add<4>(w1);
        w2 = dpp_ror_add<4>(w2);

        // 4 rows per wave; duplicate equal-value writes of w2 are benign
        if ((lane & 12) == 0) {
            const int base = row * 165 + t * 10;
            sred[base + bo]     = w0;
            sred[base + bo + 1] = w1;
            sred[base + to]     = w2;
        }

        v01 = nv01; v23 = nv23; v4 = nv4;
    }
    __syncthreads();

    // ---- final reduce: 160 threads, one (t,o) each, 32 rows ----
    if (tid < 160) {
        float sum = 0.0f;
        #pragma unroll
        for (int r = 0; r < 32; ++r)
            sum += sred[r * 165 + tid];
        scur2[tid] = sum;
    }
    __syncthreads();

    // ---- LIF-2 scan, 10 lanes ----
    if (tid < 10) {
        float m2 = 0.0f, cnt = 0.0f;
        #pragma unroll
        for (int t = 0; t < 16; ++t) {
            m2 = __builtin_fmaf(0.5f, m2, scur2[t * 10 + tid]);
            float ms = m2 - 1.0f;
            bool  sp = ms > 0.0f;
            m2  = sp ? ms : m2;
            cnt += sp ? 1.0f : 0.0f;
        }
        out[(size_t)b * 10 + tid] = cnt;
    }
}

extern "C" void kernel_launch(void* const* d_in, const int* in_sizes, int n_in,
                              void* d_out, int out_size, void* d_ws, size_t ws_size,
                              hipStream_t stream) {
    const float* x      = (const float*)d_in[0];  // 4096*784
    const float* conv_w = (const float*)d_in[1];  // 72
    const float* fc_w   = (const float*)d_in[2];  // 13520
    float* out          = (float*)d_out;          // 40960

    const int B = in_sizes[0] / 784;              // 4096
    snn_fused_kernel<<<B, 512, 0, stream>>>(x, conv_w, fc_w, out);
}